// Round 7
// baseline (78.658 us; speedup 1.0000x reference)
//
#include <hip/hip_runtime.h>

#define RNODES 1152
#define KDIM 9216                 // 1152*8
#define COUT 16
#define NCAPS 10
#define WSTRIDE (KDIM*COUT)       // 147456 floats per capsule

#define LROW 40                   // 32 k + 8 pad (ushorts) -> 80B rows (proven: ~0 conflicts)
#define WBUF (NCAPS*COUT*LROW)    // 6400 ushorts = 12.8 KB per 32k buffer
#define DSTEPS 9                  // double-steps of 64k; K-chunk = 576
#define SPLITS 16                 // 16 * 576 = 9216 = KDIM
#define MTILES 16                 // 16-row M-tiles
#define NBLK 256                  // 16 mt x 16 ks = 1 block/CU
#define PARTL (MTILES*COUT*NCAPS) // 2560 floats per block partial
#define PARTL4 (PARTL/4)          // 640

using bf16x8 = __attribute__((ext_vector_type(8))) short;
using f32x4  = __attribute__((ext_vector_type(4))) float;

// round-to-nearest (ties up), 2 ops; packed pair -> one u32 (lo | hi<<16)
__device__ __forceinline__ unsigned int pack2(float lo, float hi) {
  unsigned int a = __builtin_bit_cast(unsigned int, lo);
  unsigned int b = __builtin_bit_cast(unsigned int, hi);
  return ((a + 0x8000u) >> 16) | ((b + 0x8000u) & 0xFFFF0000u);
}
__device__ __forceinline__ unsigned short f2bf(float f) {
  unsigned int u = __builtin_bit_cast(unsigned int, f);
  return (unsigned short)((u + 0x8000u) >> 16);
}

// grid = 256. bid = mt*16 + ks -> XCD = ks%8: all 16 blocks sharing W-slice ks
// sit on ONE XCD -> W is 1 HBM fetch + 15 L2 hits. Block: 16-row M-tile,
// K-chunk 576 = 9 double-steps of 64k. Per double-step: stage W as bf16
// k-PAIRS (one ds_write_b32 per 2 values -> half the LDS write instrs of R6),
// ONE barrier, then 2x(A-frag direct from global + 2-3 MFMA per wave).
// Waves split capsules 3/3/2/2; partials 2.6 MB (was 5.2).
__global__ __launch_bounds__(256, 1) void caps_gemm(const float* __restrict__ x,
                                                    const float* __restrict__ W,
                                                    float* __restrict__ ws) {
  __shared__ unsigned short wbuf[4][WBUF];   // 4 rotating 32k buffers, 51.2 KB
  const int tid = threadIdx.x;
  const int bid = blockIdx.x;
  const int mt  = bid >> 4;         // 0..15
  const int ks  = bid & 15;         // 0..15
  const int b0  = mt * MTILES;
  const int k0  = ks * (DSTEPS * 64);   // 576-element K chunk

  const int lane = tid & 63;
  const int wv   = tid >> 6;
  const int q    = lane >> 4;       // k-quad
  const int m16  = lane & 15;

  // capsule split 3/3/2/2
  const int ncap = (wv < 2) ? 3 : 2;
  const int cap0 = (wv < 2) ? wv * 3 : 6 + (wv - 2) * 2;

  // ---- staging decode: 1280 units per double-step, unit u = j*256 + tid ----
  // kp = u&15 (k-pair), cc = (u>>4)%40 (col-quad: n=cc>>2, o4=(cc&3)*4),
  // sub = u/640 (which 32k half). Wave-coalesced: lanes t,t+16,t+32,t+48 cover
  // one full 64B W k-row.
  int u_cc[5], u_kp[5], u_sub[5];
#pragma unroll
  for (int j = 0; j < 5; ++j) {
    const int u = j * 256 + tid;
    u_kp[j]  = u & 15;
    u_cc[j]  = (u >> 4) % 40;
    u_sub[j] = u / 640;
  }

  const float* xrow = x + (size_t)(b0 + m16) * KDIM + k0 + q * 8;

  float4 pw[2][5][2];     // [ds parity][unit][k-pair elem]
  float4 xa[2][2][2];     // [ds parity][sub][half of 8k]

  auto load_w = [&](int ds, int slot) {
#pragma unroll
    for (int j = 0; j < 5; ++j) {
      const int n  = u_cc[j] >> 2, o4 = (u_cc[j] & 3) << 2;
      const float* base = W + (size_t)n * WSTRIDE +
                          (size_t)(k0 + ds * 64 + u_sub[j] * 32 + 2 * u_kp[j]) * COUT + o4;
      pw[slot][j][0] = *(const float4*)(base);
      pw[slot][j][1] = *(const float4*)(base + COUT);
    }
  };
  auto load_x = [&](int ds, int slot) {
#pragma unroll
    for (int sub = 0; sub < 2; ++sub) {
      xa[slot][sub][0] = *(const float4*)(xrow + ds * 64 + sub * 32);
      xa[slot][sub][1] = *(const float4*)(xrow + ds * 64 + sub * 32 + 4);
    }
  };

  load_w(0, 0);
  load_w(1, 1);
  load_x(0, 0);

  f32x4 acc[3];
#pragma unroll
  for (int i = 0; i < 3; ++i) acc[i] = (f32x4){0.f, 0.f, 0.f, 0.f};

  for (int ds = 0; ds < DSTEPS; ++ds) {
    const int par = ds & 1;
    // ---- stage W double-step ds: packed k-pair b32 writes ----
#pragma unroll
    for (int j = 0; j < 5; ++j) {
      const int n  = u_cc[j] >> 2, o4 = (u_cc[j] & 3) << 2;
      unsigned int* b32 =
          (unsigned int*)&wbuf[par * 2 + u_sub[j]][(n * COUT + o4) * LROW + 2 * u_kp[j]];
      const int lr2 = LROW / 2;   // 20 u32 per col row
#pragma unroll
      for (int r = 0; r < 4; ++r)
        b32[r * lr2] = pack2(pw[par][j][0][r], pw[par][j][1][r]);
    }
    __syncthreads();
    // reads(ds) finish before barrier(ds+1); writes reusing these buffers
    // happen in iter ds+2 after that barrier -> safe with 1 barrier/double-step.

    if (ds + 2 < DSTEPS) load_w(ds + 2, par);
    if (ds + 1 < DSTEPS) load_x(ds + 1, (ds + 1) & 1);

#pragma unroll
    for (int sub = 0; sub < 2; ++sub) {
      const unsigned short* b = &wbuf[par * 2 + sub][0];
      uint4 av;
      av.x = pack2(xa[par][sub][0].x, xa[par][sub][0].y);
      av.y = pack2(xa[par][sub][0].z, xa[par][sub][0].w);
      av.z = pack2(xa[par][sub][1].x, xa[par][sub][1].y);
      av.w = pack2(xa[par][sub][1].z, xa[par][sub][1].w);
      const bf16x8 a = __builtin_bit_cast(bf16x8, av);
#pragma unroll
      for (int j = 0; j < 3; ++j) {
        if (j < ncap) {
          const int nt = cap0 + j;
          bf16x8 bf = *(const bf16x8*)&b[(nt * COUT + m16) * LROW + q * 8];
          acc[j] = __builtin_amdgcn_mfma_f32_16x16x32_bf16(a, bf, acc[j], 0, 0, 0);
        }
      }
    }
  }

  // ---- partial store: P[bid][cap][row16][o]  (C/D: col=m16=o, row=q*4+r) ----
  float* P = ws + (size_t)bid * PARTL;
#pragma unroll
  for (int j = 0; j < 3; ++j) {
    if (j < ncap) {
#pragma unroll
      for (int r = 0; r < 4; ++r)
        P[(cap0 + j) * 256 + (q * 4 + r) * COUT + m16] = acc[j][r];
    }
  }
}

// grid = 160 x 64: thread f owns output float4 f (f = n*1024 + b*4 + o4),
// sums 16 splits in fixed order (deterministic), squashes over 4-lane o-groups.
__global__ __launch_bounds__(64, 1) void caps_reduce(const float* __restrict__ ws,
                                                     float* __restrict__ out) {
  const int f  = blockIdx.x * 64 + threadIdx.x;   // 0..10239
  const int n  = f >> 10;
  const int b  = (f >> 2) & 255;
  const int o4 = f & 3;
  const int mt = b >> 4, row = b & 15;

  const float4* base = (const float4*)ws + (size_t)(mt * SPLITS) * PARTL4
                       + n * 64 + row * 4 + o4;
  float4 s0 = {0,0,0,0}, s1 = {0,0,0,0}, s2 = {0,0,0,0}, s3 = {0,0,0,0};
#pragma unroll
  for (int kk = 0; kk < SPLITS; kk += 4) {
    float4 a0 = base[(size_t)(kk + 0) * PARTL4];
    float4 a1 = base[(size_t)(kk + 1) * PARTL4];
    float4 a2 = base[(size_t)(kk + 2) * PARTL4];
    float4 a3 = base[(size_t)(kk + 3) * PARTL4];
    s0.x += a0.x; s0.y += a0.y; s0.z += a0.z; s0.w += a0.w;
    s1.x += a1.x; s1.y += a1.y; s1.z += a1.z; s1.w += a1.w;
    s2.x += a2.x; s2.y += a2.y; s2.z += a2.z; s2.w += a2.w;
    s3.x += a3.x; s3.y += a3.y; s3.z += a3.z; s3.w += a3.w;
  }
  const float inv = 1.0f / (float)RNODES;
  float4 s;
  s.x = ((s0.x + s1.x) + (s2.x + s3.x)) * inv;
  s.y = ((s0.y + s1.y) + (s2.y + s3.y)) * inv;
  s.z = ((s0.z + s1.z) + (s2.z + s3.z)) * inv;
  s.w = ((s0.w + s1.w) + (s2.w + s3.w)) * inv;

  float sq = s.x * s.x + s.y * s.y + s.z * s.z + s.w * s.w;
  sq += __shfl_xor(sq, 1);   // o-group of 16 = 4 adjacent lanes (o4 = f&3)
  sq += __shfl_xor(sq, 2);
  const float g = sqrtf(sq) / (1.0f + sq);
  s.x *= g; s.y *= g; s.z *= g; s.w *= g;

  ((float4*)out)[f] = s;     // out float4 index == f by construction
}

extern "C" void kernel_launch(void* const* d_in, const int* in_sizes, int n_in,
                              void* d_out, int out_size, void* d_ws, size_t ws_size,
                              hipStream_t stream) {
  const float* x = (const float*)d_in[0];   // [256,1152,8] fp32
  const float* W = (const float*)d_in[1];   // [10,1152,8,16] fp32
  float* ws  = (float*)d_ws;                // 256*2560 fp32 partials (2.6 MB)
  float* out = (float*)d_out;               // 40960 fp32

  caps_gemm<<<dim3(NBLK), dim3(256), 0, stream>>>(x, W, ws);
  caps_reduce<<<dim3(160), dim3(64), 0, stream>>>(ws, out);
}

// Round 8
// 71.236 us; speedup vs baseline: 1.1042x; 1.1042x over previous
//
#include <hip/hip_runtime.h>

#define RNODES 1152
#define KDIM 9216                 // 1152*8
#define COUT 16
#define NCAPS 10
#define WSTRIDE (KDIM*COUT)       // 147456 floats per capsule

#define LROW 40                   // 32 k + 8 pad (ushorts) -> 80B rows, 16B-aligned reads
#define WBUF (NCAPS*COUT*LROW)    // 6400 ushorts = 12.8 KB per buffer
#define STEPS 9                   // k-steps of 32 per block
#define SPLITS 32                 // 32 * 9 * 32 = 9216 = KDIM
#define NBLK 256                  // 8 M-tiles x 32 splits = 1 block/CU exactly
#define PARTL (32*COUT*NCAPS)     // 5120 floats per block partial (32 rows)
#define PARTL4 (PARTL/4)          // 1280 float4

using bf16x8 = __attribute__((ext_vector_type(8))) short;
using f32x4  = __attribute__((ext_vector_type(4))) float;

// round-to-nearest (ties up): 2 VALU ops; unbiased to 2^-9 rel — same as R6.
__device__ __forceinline__ unsigned short f2bf(float f) {
  unsigned int u = __builtin_bit_cast(unsigned int, f);
  return (unsigned short)((u + 0x8000u) >> 16);
}

// grid = 256 (one block/CU). bid = mt*32 + ks -> XCD = ks%8: all 8 mt-blocks
// sharing W-slice ks sit on ONE XCD -> W re-reads are L2 hits.
//
// R8 change vs R6 (everything else identical):
//  * W staging decode is slab-contiguous: unit u = j*256+tid -> n=u>>7,
//    kl=(u&127)>>2, o4=(u&3)*4. Consecutive lanes read consecutive 16B ->
//    every W load is a 1KB fully-coalesced wave transaction (R6's decode put
//    adjacent lanes 64B apart = 4x TA work; R7 proved gather cost dominates).
//  * LDS layout adds an 8-element k-block rotation so the new write pattern
//    stays conflict-free: col c stores k-block t at position
//    (t + (c&3) + ((c>>2)&3)) & 3. Writes: lanes 0-3 (cols {0,4,12,8}+r,
//    same kl) land on banks {0,20,8,28} -> 2-way overall (free, m136).
//    Reads: b128 at (c*LROW + 8*q') with q' = (q + (m16&3) + (m16>>2)) & 3 —
//    capsule-independent since nt*16 ≡ 0 (mod 4); still 16B-aligned contiguous.
__global__ __launch_bounds__(256, 1) void caps_gemm(const float* __restrict__ x,
                                                    const float* __restrict__ W,
                                                    float* __restrict__ ws) {
  __shared__ unsigned short wbuf[2][WBUF];   // ping-pong, 25.6 KB
  const int tid = threadIdx.x;
  const int bid = blockIdx.x;
  const int mt  = bid >> 5;         // 0..7  (32-row M-tile)
  const int ks  = bid & 31;         // 0..31 (K split)
  const int b0  = mt * 32;
  const int k0  = ks * (STEPS * 32);   // 288-element K chunk

  const int lane = tid & 63;
  const int wv   = tid >> 6;
  const int p    = wv >> 1;         // row half
  const int h    = wv & 1;          // capsule half
  const int q    = lane >> 4;       // k-quad
  const int m16  = lane & 15;

  // ---- slab-contiguous staging decode (5 units/thread covers 1280 float4) ----
  int u_n[5], u_kl[5], u_of[5];
#pragma unroll
  for (int j = 0; j < 5; ++j) {
    const int u  = j * 256 + tid;
    u_n[j]  = u >> 7;               // capsule slab 0..9
    const int rem = u & 127;
    u_kl[j] = rem >> 2;             // k within step, 0..31
    u_of[j] = (rem & 3) << 2;       // o-quad base 0,4,8,12
  }

  const float* xrow = x + (size_t)(b0 + p * 16 + m16) * KDIM + k0 + q * 8;

  float4 pw[3][5];
  float4 pa[3][2];

  auto load_step = [&](int s, int slot) {
#pragma unroll
    for (int j = 0; j < 5; ++j)
      pw[slot][j] = *(const float4*)(W + (size_t)u_n[j] * WSTRIDE +
                                     (size_t)(k0 + s * 32 + u_kl[j]) * COUT + u_of[j]);
    pa[slot][0] = *(const float4*)(xrow + s * 32);
    pa[slot][1] = *(const float4*)(xrow + s * 32 + 4);
  };

  load_step(0, 0);
  load_step(1, 1);
  load_step(2, 2);

  f32x4 acc[5];
#pragma unroll
  for (int i = 0; i < 5; ++i) acc[i] = (f32x4){0.f, 0.f, 0.f, 0.f};

  // per-lane rotated read quad (k-block) — same for every capsule
  const int qrot = (q + (m16 & 3) + (m16 >> 2)) & 3;

#pragma unroll
  for (int s = 0; s < STEPS; ++s) {
    const int slot = s % 3;
    unsigned short* b = &wbuf[s & 1][0];
    // stage W step s: [col][k-rotated] bf16 transpose
#pragma unroll
    for (int j = 0; j < 5; ++j) {
      const int kl  = u_kl[j];
      const int klo = kl & 7, kblk = kl >> 3;
      const float* v = (const float*)&pw[slot][j];
#pragma unroll
      for (int r = 0; r < 4; ++r) {
        const int c   = u_n[j] * COUT + u_of[j] + r;
        const int pos = klo | (((kblk + (c & 3) + ((c >> 2) & 3)) & 3) << 3);
        b[c * LROW + pos] = f2bf(v[r]);
      }
    }
    __syncthreads();
    // write(s+2) to this parity happens after barrier(s+1); reads(s) drain
    // before barrier(s+1) -> classic 2-buffer safety, 1 barrier/step.

    bf16x8 a;
    a[0] = (short)f2bf(pa[slot][0].x); a[1] = (short)f2bf(pa[slot][0].y);
    a[2] = (short)f2bf(pa[slot][0].z); a[3] = (short)f2bf(pa[slot][0].w);
    a[4] = (short)f2bf(pa[slot][1].x); a[5] = (short)f2bf(pa[slot][1].y);
    a[6] = (short)f2bf(pa[slot][1].z); a[7] = (short)f2bf(pa[slot][1].w);

    if (s + 3 < STEPS) load_step(s + 3, slot);   // slot just freed

#pragma unroll
    for (int j = 0; j < 5; ++j) {
      const int nt = h * 5 + j;
      bf16x8 bf = *(const bf16x8*)&b[(nt * COUT + m16) * LROW + (qrot << 3)];
      acc[j] = __builtin_amdgcn_mfma_f32_16x16x32_bf16(a, bf, acc[j], 0, 0, 0);
    }
  }

  // ---- partial store: P[bid][n][row32][o] ----
  float* P = ws + (size_t)bid * PARTL;
  const int prow = p * 16 + q * 4;   // C/D: col=lane&15 (=o), row=q*4+reg
#pragma unroll
  for (int j = 0; j < 5; ++j)
#pragma unroll
    for (int r = 0; r < 4; ++r)
      P[(h * 5 + j) * 512 + (prow + r) * COUT + m16] = acc[j][r];
}

// grid = 80 x 128: thread f owns output float4 f (f = n*1024 + b*4 + o4),
// sums 32 splits with fixed order (deterministic), squashes over 4-lane o-groups.
__global__ __launch_bounds__(128, 1) void caps_reduce(const float* __restrict__ ws,
                                                      float* __restrict__ out) {
  const int f  = blockIdx.x * 128 + threadIdx.x;   // 0..10239
  const int n  = f >> 10;
  const int b  = (f >> 2) & 255;
  const int o4 = f & 3;
  const int mt = b >> 5, row = b & 31;

  const float4* base = (const float4*)ws + (size_t)(mt * SPLITS) * PARTL4
                       + n * 128 + row * 4 + o4;
  float4 s0 = {0,0,0,0}, s1 = {0,0,0,0}, s2 = {0,0,0,0}, s3 = {0,0,0,0};
#pragma unroll
  for (int kk = 0; kk < SPLITS; kk += 4) {
    float4 a0 = base[(size_t)(kk + 0) * PARTL4];
    float4 a1 = base[(size_t)(kk + 1) * PARTL4];
    float4 a2 = base[(size_t)(kk + 2) * PARTL4];
    float4 a3 = base[(size_t)(kk + 3) * PARTL4];
    s0.x += a0.x; s0.y += a0.y; s0.z += a0.z; s0.w += a0.w;
    s1.x += a1.x; s1.y += a1.y; s1.z += a1.z; s1.w += a1.w;
    s2.x += a2.x; s2.y += a2.y; s2.z += a2.z; s2.w += a2.w;
    s3.x += a3.x; s3.y += a3.y; s3.z += a3.z; s3.w += a3.w;
  }
  const float inv = 1.0f / (float)RNODES;
  float4 s;
  s.x = ((s0.x + s1.x) + (s2.x + s3.x)) * inv;
  s.y = ((s0.y + s1.y) + (s2.y + s3.y)) * inv;
  s.z = ((s0.z + s1.z) + (s2.z + s3.z)) * inv;
  s.w = ((s0.w + s1.w) + (s2.w + s3.w)) * inv;

  float sq = s.x * s.x + s.y * s.y + s.z * s.z + s.w * s.w;
  sq += __shfl_xor(sq, 1);   // o-group of 16 = 4 adjacent lanes (o4 = f&3)
  sq += __shfl_xor(sq, 2);
  const float g = sqrtf(sq) / (1.0f + sq);
  s.x *= g; s.y *= g; s.z *= g; s.w *= g;

  ((float4*)out)[f] = s;     // out float4 index == f by construction
}

extern "C" void kernel_launch(void* const* d_in, const int* in_sizes, int n_in,
                              void* d_out, int out_size, void* d_ws, size_t ws_size,
                              hipStream_t stream) {
  const float* x = (const float*)d_in[0];   // [256,1152,8] fp32
  const float* W = (const float*)d_in[1];   // [10,1152,8,16] fp32
  float* ws  = (float*)d_ws;                // 256*5120 fp32 partials (5.2 MB)
  float* out = (float*)d_out;               // 40960 fp32

  caps_gemm<<<dim3(NBLK), dim3(256), 0, stream>>>(x, W, ws);
  caps_reduce<<<dim3(80), dim3(128), 0, stream>>>(ws, out);
}